// Round 30
// baseline (102.200 us; speedup 1.0000x reference)
//
#include <hip/hip_runtime.h>

#define NP_   16384
#define NQ_   8192
#define NB_   2
#define K_    16
#define TPB   256
#define PTPB  1024

#define GD    20
#define G3    (GD*GD*GD)          // 8000 cells per batch
#define ORG   (-4.25f)
#define W     (8.5f / 20.0f)      // 0.425
#define INVW  (20.0f / 8.5f)

#define IDX_OFF 0
#define RS_OFF  (NB_*NQ_*K_)      // 262144
#define RS_N    (NB_*NQ_+1)       // 16385
#define DST_OFF (RS_OFF + RS_N)   // 278529

typedef unsigned long long ull;
typedef float f32x2 __attribute__((ext_vector_type(2)));

__device__ __forceinline__ int mbcnt64(ull m) {
    return __builtin_amdgcn_mbcnt_hi((unsigned)(m >> 32),
           __builtin_amdgcn_mbcnt_lo((unsigned)m, 0));
}

__device__ __forceinline__ int cell_of(float x, float y, float z) {
    int ix = (int)floorf((x - ORG) * INVW); ix = min(max(ix, 0), GD-1);
    int iy = (int)floorf((y - ORG) * INVW); iy = min(max(iy, 0), GD-1);
    int iz = (int)floorf((z - ORG) * INVW); iz = min(max(iz, 0), GD-1);
    return (ix*GD + iy)*GD + iz;
}

// ---------------- build kernels ----------------
__global__ void knn_hist(const float* __restrict__ pts, int* __restrict__ counts) {
    int i = blockIdx.x*TPB + threadIdx.x;
    if (i < NB_*NP_) {
        int b = i >> 14;
        int cid = cell_of(pts[i*3], pts[i*3+1], pts[i*3+2]);
        atomicAdd(&counts[b*(G3+1) + cid], 1);
    }
}

__global__ __launch_bounds__(PTPB) void knn_prefix(int* __restrict__ counts,
                                                   int* __restrict__ cursors) {
    const int CPT = (G3 + PTPB - 1) / PTPB;   // 8 (guarded)
    int b = blockIdx.x, tid = threadIdx.x;
    int lane = tid & 63, w = tid >> 6;        // 16 waves
    int* cnt = counts + b*(G3+1);
    int base = tid * CPT;
    int tsum = 0;
    for (int j = 0; j < CPT; ++j) { int ix = base+j; if (ix < G3) tsum += cnt[ix]; }
    int v = tsum;
    #pragma unroll
    for (int off = 1; off < 64; off <<= 1) {
        int t = __shfl_up(v, off);
        if (lane >= off) v += t;
    }
    __shared__ int wsum[PTPB/64];
    if (lane == 63) wsum[w] = v;
    __syncthreads();
    int wbase = 0;
    for (int k = 0; k < w; ++k) wbase += wsum[k];
    int run = wbase + v - tsum;               // exclusive base for this thread
    for (int j = 0; j < CPT; ++j) {
        int ix = base+j;
        if (ix < G3) {
            int c = cnt[ix];
            cnt[ix] = run;
            cursors[b*G3 + ix] = run;
            run += c;
        }
    }
    if (tid == PTPB-1) cnt[G3] = run;         // sentinel = 16384
}

__global__ void knn_scatter(const float* __restrict__ pts, int* __restrict__ cursors,
                            float4* __restrict__ sorted) {
    int i = blockIdx.x*TPB + threadIdx.x;
    if (i < NB_*NP_) {
        int b = i >> 14, loc = i & (NP_-1);
        float x = pts[i*3], y = pts[i*3+1], z = pts[i*3+2];
        int cid = cell_of(x, y, z);
        int pos = atomicAdd(&cursors[b*G3 + cid], 1);
        sorted[(size_t)b*NP_ + pos] = make_float4(x, y, z, __int_as_float(loc));
    }
}

// ---------------- search kernel (own-cell bootstrap, pipelined batches) ----------------
__global__ __launch_bounds__(TPB, 4) void knn_search(
        const float* __restrict__ qrs,
        const int* __restrict__ starts,
        const float4* __restrict__ sorted,
        float* __restrict__ out)
{
    // Validated exact-match formula (R6): sq,sp fwd noFMA; ip fwd FMA chain;
    // d = fmaf(-2, ip, sq+sp). Candidates sorted by lex (d, idx) -> stable.
    #pragma clang fp contract(off)
    __shared__ float2 buf[4][128];

    const int tid  = threadIdx.x;
    const int lane = tid & 63;
    const int wv   = tid >> 6;
    const int gq   = blockIdx.x*4 + wv;
    const int batch = gq >> 13;
    const int gofs  = batch * NP_;
    const int sb    = batch * (G3+1);
    const float4* spts = sorted + (size_t)batch * NP_;

    const float qx = qrs[gq*3+0], qy = qrs[gq*3+1], qz = qrs[gq*3+2];
    const float sq = qx*qx + qy*qy + qz*qz;   // fwd, no FMA

    int cx = (int)floorf((qx - ORG) * INVW); cx = min(max(cx,0), GD-1);
    int cy = (int)floorf((qy - ORG) * INVW); cy = min(max(cy,0), GD-1);
    int cz = (int)floorf((qz - ORG) * INVW); cz = min(max(cz,0), GD-1);

    const float INF = __int_as_float(0x7f800000);
    float md = INF; int mi = 0x7fffffff;      // master sorted-16 (lanes 0-15)
    float th = INF;
    int cnt = 0;

    auto drain = [&]() {
        int rounds = (cnt + 63) >> 6;
        for (int r = 0; r < rounds; ++r) {
            int pos = (r << 6) + lane;
            float nd = INF; int ni = 0x7fffffff;
            if (pos < cnt) { float2 e = buf[wv][pos]; nd = e.x; ni = __float_as_int(e.y); }
            // 64-lane bitonic sort ascending by (d, idx)
            #pragma unroll
            for (int m = 2; m <= 64; m <<= 1) {
                #pragma unroll
                for (int j = m >> 1; j >= 1; j >>= 1) {
                    float od = __shfl_xor(nd, j);
                    int   oi = __shfl_xor(ni, j);
                    bool pl = (od < nd) || (od == nd && oi < ni);
                    bool keepmin = ((lane & j) == 0) == ((lane & m) == 0);
                    if (keepmin == pl) { nd = od; ni = oi; }
                }
            }
            // Batcher halver: master[s] vs cand[15-s]
            float cd = __shfl(nd, 15 - (lane & 15));
            int   ci = __shfl(ni, 15 - (lane & 15));
            bool take = (cd < md) || (cd == md && ci < mi);
            if (take) { md = cd; mi = ci; }
            #pragma unroll
            for (int j = 8; j >= 1; j >>= 1) {
                float od = __shfl_xor(md, j, 16);
                int   oi = __shfl_xor(mi, j, 16);
                bool pl = (od < md) || (od == md && oi < mi);
                if ((((lane & 15) & j) == 0) == pl) { md = od; mi = oi; }
            }
        }
        cnt = 0;
        th = __shfl(md, 15);                  // current 16th-best (INF if <16)
    };

    // process one loaded candidate batch: distance, filter, append
    auto process = [&](float4 p, bool act) {
        float d = INF; int idx = 0x7fffffff;
        if (act) {
            float spw = p.x*p.x + p.y*p.y + p.z*p.z;   // fwd, no FMA
            float ip = fmaf(p.z, qz, fmaf(p.y, qy, __fmul_rn(p.x, qx)));
            d = fmaf(-2.0f, ip, sq + spw);
            idx = __float_as_int(p.w);
        }
        bool pass = act && (d <= th);          // <= : tie-safe superset
        ull mk = __ballot(pass);
        if (mk) {
            int sl = cnt + mbcnt64(mk);
            if (pass) buf[wv][sl] = make_float2(d, __int_as_float(idx));
            cnt += (int)__popcll(mk);
            if (cnt >= 64) drain();            // max before = 63, +64 <= 127
        }
    };

    // ---- bootstrap: own cell first (coalesced), establishes finite th ----
    {
        int cid0 = (cx*GD + cy)*GD + cz;
        int st0 = starts[sb + cid0];
        int n0  = starts[sb + cid0 + 1] - st0;
        for (int b0 = 0; b0 < n0; b0 += 64) {
            int o = b0 + lane;
            bool act = o < n0;
            float4 p = make_float4(0,0,0,0);
            if (act) p = spts[st0 + o];
            process(p, act);
        }
        if (cnt > 0) drain();
    }

    for (int R = 1; R <= GD; ++R) {
        const int S = 2*R + 1;
        const int F = S*S;
        const int lat = 4*(S-1);
        const int total = (R == 1) ? 27 : (2*F + (S-2)*lat);

        for (int cb = 0; cb < total; cb += 64) {
            int cidx = cb + lane;
            int n = 0, st = 0;
            if (cidx < total) {
                int di, dj, dk;
                if (R == 1) {                 // 3x3x3 box (const divisions)
                    di = cidx/9 - 1; int r9 = cidx - (cidx/9)*9;
                    dj = r9/3 - 1;   dk = r9 - (r9/3)*3 - 1;
                } else if (cidx < F) {        // -x face
                    di = -R; int t = cidx; int q = t/S; dj = q - R; dk = t - q*S - R;
                } else if (cidx < 2*F) {      // +x face
                    di =  R; int t = cidx - F; int q = t/S; dj = q - R; dk = t - q*S - R;
                } else {                      // lateral perimeter walk
                    int t = cidx - 2*F;
                    int layer = t/lat; int pos = t - layer*lat;
                    di = layer + 1 - R;       // di in (-R, R)
                    int side = pos/(S-1); int u = pos - side*(S-1);
                    if      (side == 0) { dj = -R;     dk = -R + u; }
                    else if (side == 1) { dj = -R + u; dk =  R;     }
                    else if (side == 2) { dj =  R;     dk =  R - u; }
                    else                { dj =  R - u; dk = -R;     }
                }
                bool own = (di == 0) && (dj == 0) && (dk == 0);   // already done
                int ii = cx+di, jj = cy+dj, kk = cz+dk;
                if (!own && ii>=0 && jj>=0 && kk>=0 && ii<GD && jj<GD && kk<GD) {
                    // per-cell Euclidean lower bound (th finite after bootstrap)
                    float lox = ORG + (float)ii * W;
                    float loy = ORG + (float)jj * W;
                    float loz = ORG + (float)kk * W;
                    float dx = fmaxf(0.0f, fmaxf(lox - qx, qx - (lox + W)));
                    float dy = fmaxf(0.0f, fmaxf(loy - qy, qy - (loy + W)));
                    float dz = fmaxf(0.0f, fmaxf(loz - qz, qz - (loz + W)));
                    float mind2 = dx*dx + dy*dy + dz*dz;
                    if (mind2 <= th + 1e-3f) {    // stale th only over-admits
                        int cid = (ii*GD + jj)*GD + kk;
                        st = starts[sb + cid];
                        n  = starts[sb + cid + 1] - st;
                    }
                }
            }
            // wave-wide exclusive prefix sum of n
            int pex = n;
            #pragma unroll
            for (int off = 1; off < 64; off <<= 1) {
                int t2 = __shfl_up(pex, off);
                if (lane >= off) pex += t2;
            }
            int T = __shfl(pex, 63);          // total candidates this chunk
            pex -= n;                         // exclusive prefix
            if (T == 0) continue;

            // register-only bsearch + load issue for batch starting at bb
            auto fetchB = [&](int bb, float4& p, bool& act) {
                int sI = bb + lane;
                int lo = 0;
                #pragma unroll
                for (int j = 32; j >= 1; j >>= 1) {
                    int m = lo + j;
                    int pv = __shfl(pex, m);
                    if (pv <= sI) lo = m;
                }
                int stL = __shfl(st, lo);
                int pL  = __shfl(pex, lo);
                act = sI < T;
                if (act) p = spts[stL + (sI - pL)];
            };

            // depth-2 software pipeline over batches
            float4 pA = make_float4(0,0,0,0), pB = make_float4(0,0,0,0);
            bool aA = false, aB = false;
            fetchB(0, pA, aA);
            if (64 < T) fetchB(64, pB, aB);
            for (int bb = 0; bb < T; bb += 64) {
                float4 pN = make_float4(0,0,0,0); bool aN = false;
                if (bb + 128 < T) fetchB(bb + 128, pN, aN);
                process(pA, aA);
                pA = pB; aA = aB;
                pB = pN; aB = aN;
            }
        }
        if (cnt > 0) drain();                  // tighten th for next shell's prune
        // termination (th only shrinks -> conservative)
        float bd = INF;
        if (cx - R > 0)      bd = fminf(bd, qx - (ORG + (float)(cx - R) * W));
        if (cx + R < GD - 1) bd = fminf(bd, (ORG + (float)(cx + R + 1) * W) - qx);
        if (cy - R > 0)      bd = fminf(bd, qy - (ORG + (float)(cy - R) * W));
        if (cy + R < GD - 1) bd = fminf(bd, (ORG + (float)(cy + R + 1) * W) - qy);
        if (cz - R > 0)      bd = fminf(bd, qz - (ORG + (float)(cz - R) * W));
        if (cz + R < GD - 1) bd = fminf(bd, (ORG + (float)(cz + R + 1) * W) - qz);
        if (bd * bd > th + 1e-3f) break;       // margin >> formula/geom error
    }
    drain();                                   // flush leftovers before output

    if (lane < K_) {
        out[IDX_OFF + gq*K_ + lane] = (float)(mi + gofs);
        out[DST_OFF + gq*K_ + lane] = fmaxf(md, 0.0f);
    }
    int gt = blockIdx.x*TPB + tid;
    if (gt < RS_N) out[RS_OFF + gt] = (float)(gt * K_);
}

// ---------------- fallback: R21 kernel (passed, 114 us) ----------------
#define QPB   16
#define TILE  1024
#define NTILES (NP_/TILE)
#define GPT   (TILE/64)
#define CBUF  80

__global__ __launch_bounds__(TPB, 4) void knn_fallback(const float* __restrict__ pts,
                                                       const float* __restrict__ qrs,
                                                       float* __restrict__ out)
{
    #pragma clang fp contract(off)
    __shared__ float4 tile[TILE];
    __shared__ float2 buf[QPB][CBUF];
    const int tid  = threadIdx.x;
    const int lane = tid & 63;
    const int s    = lane & 15;
    const int g    = lane >> 4;
    const int bq   = tid >> 4;
    const int gq   = blockIdx.x * QPB + bq;
    const int batch = gq >> 13;
    const int gofs  = batch * NP_;
    const float* pb = pts + (size_t)gofs * 3;
    const int qb   = (tid >> 6) << 2;
    float qxv[4], qyv[4], qzv[4], sqv[4];
    #pragma unroll
    for (int qi = 0; qi < 4; ++qi) {
        const float* qp = qrs + (size_t)(blockIdx.x * QPB + qb + qi) * 3;
        qxv[qi] = qp[0]; qyv[qi] = qp[1]; qzv[qi] = qp[2];
        sqv[qi] = qxv[qi]*qxv[qi] + qyv[qi]*qyv[qi] + qzv[qi]*qzv[qi];
    }
    const f32x2 qx01 = {qxv[0], qxv[1]}, qx23 = {qxv[2], qxv[3]};
    const f32x2 qy01 = {qyv[0], qyv[1]}, qy23 = {qyv[2], qyv[3]};
    const f32x2 qz01 = {qzv[0], qzv[1]}, qz23 = {qzv[2], qzv[3]};
    const f32x2 sq01 = {sqv[0], sqv[1]}, sq23 = {sqv[2], sqv[3]};
    const f32x2 n2   = {-2.0f, -2.0f};
    const float INF = __int_as_float(0x7f800000);
    float hd = INF; int hi = 0x7fffffff;
    float th0 = INF, th1 = INF, th2 = INF, th3 = INF;
    int cnt0 = 0, cnt1 = 0, cnt2 = 0, cnt3 = 0;
    auto drain = [&]() {
        int cmax = max(max(cnt0, cnt1), max(cnt2, cnt3));
        int mycnt = (g==0) ? cnt0 : (g==1) ? cnt1 : (g==2) ? cnt2 : cnt3;
        for (int r = 0; r < cmax; r += K_) {
            float nd = INF; int ni = 0x7fffffff;
            int pos = r + s;
            if (pos < mycnt) { float2 e = buf[bq][pos]; nd = e.x; ni = __float_as_int(e.y); }
            #pragma unroll
            for (int m = 2; m <= 16; m <<= 1) {
                #pragma unroll
                for (int j = m >> 1; j > 0; j >>= 1) {
                    float od = __shfl_xor(nd, j);
                    int   oi = __shfl_xor(ni, j);
                    bool pl = (od < nd) || (od == nd && oi < ni);
                    bool keepmin = ((s & j) == 0) == ((s & m) == 0);
                    if (keepmin == pl) { nd = od; ni = oi; }
                }
            }
            float od = __shfl_xor(nd, 15);
            int   oi = __shfl_xor(ni, 15);
            bool pl = (od < hd) || (od == hd && oi < hi);
            if (pl) { hd = od; hi = oi; }
            #pragma unroll
            for (int j = 8; j > 0; j >>= 1) {
                float od2 = __shfl_xor(hd, j);
                int   oi2 = __shfl_xor(hi, j);
                bool pl2 = (od2 < hd) || (od2 == hd && oi2 < hi);
                if (((s & j) == 0) == pl2) { hd = od2; hi = oi2; }
            }
        }
        cnt0 = cnt1 = cnt2 = cnt3 = 0;
        th0 = __shfl(hd, 15, 64); th1 = __shfl(hd, 31, 64);
        th2 = __shfl(hd, 47, 64); th3 = __shfl(hd, 63, 64);
    };
    for (int t = 0; t < NTILES; ++t) {
        __syncthreads();
        #pragma unroll
        for (int k = 0; k < TILE/TPB; ++k) {
            int lp = tid + k*TPB; int gp = t*TILE + lp;
            float x = pb[gp*3+0], y = pb[gp*3+1], z = pb[gp*3+2];
            float sp = x*x + y*y + z*z;
            tile[lp] = make_float4(x, y, z, sp);
        }
        __syncthreads();
        #pragma unroll 4
        for (int gi = 0; gi < GPT; ++gi) {
            float4 p = tile[gi*64 + lane];
            f32x2 x2 = {p.x, p.x}, y2 = {p.y, p.y}, z2 = {p.z, p.z};
            f32x2 sps = {p.w, p.w};
            f32x2 ip01 = __builtin_elementwise_fma(z2, qz01,
                         __builtin_elementwise_fma(y2, qy01, x2*qx01));
            f32x2 ip23 = __builtin_elementwise_fma(z2, qz23,
                         __builtin_elementwise_fma(y2, qy23, x2*qx23));
            f32x2 d01 = __builtin_elementwise_fma(n2, ip01, sq01 + sps);
            f32x2 d23 = __builtin_elementwise_fma(n2, ip23, sq23 + sps);
            float d0 = d01.x, d1 = d01.y, d2 = d23.x, d3 = d23.y;
            ull m0 = __ballot(d0 <= th0);
            ull m1 = __ballot(d1 <= th1);
            ull m2 = __ballot(d2 <= th2);
            ull m3 = __ballot(d3 <= th3);
            if (m0 | m1 | m2 | m3) {
                const float fpid = __int_as_float(t*TILE + gi*64 + lane);
                if (m0) { int sl = cnt0 + mbcnt64(m0);
                    if (d0 <= th0) buf[qb+0][sl] = make_float2(d0, fpid);
                    cnt0 += (int)__popcll(m0); }
                if (m1) { int sl = cnt1 + mbcnt64(m1);
                    if (d1 <= th1) buf[qb+1][sl] = make_float2(d1, fpid);
                    cnt1 += (int)__popcll(m1); }
                if (m2) { int sl = cnt2 + mbcnt64(m2);
                    if (d2 <= th2) buf[qb+2][sl] = make_float2(d2, fpid);
                    cnt2 += (int)__popcll(m2); }
                if (m3) { int sl = cnt3 + mbcnt64(m3);
                    if (d3 <= th3) buf[qb+3][sl] = make_float2(d3, fpid);
                    cnt3 += (int)__popcll(m3); }
                if ((cnt0 | cnt1 | cnt2 | cnt3) >= K_) drain();
            }
        }
    }
    drain();
    out[IDX_OFF + gq*K_ + s] = (float)(hi + gofs);
    out[DST_OFF + gq*K_ + s] = fmaxf(hd, 0.0f);
    int gt = blockIdx.x * TPB + tid;
    if (gt < RS_N) out[RS_OFF + gt] = (float)(gt * K_);
}

extern "C" void kernel_launch(void* const* d_in, const int* in_sizes, int n_in,
                              void* d_out, int out_size, void* d_ws, size_t ws_size,
                              hipStream_t stream)
{
    const float* pts = (const float*)d_in[0];
    const float* qrs = (const float*)d_in[1];
    float* out = (float*)d_out;
    (void)in_sizes; (void)n_in; (void)out_size;

    const size_t counts_ints = (size_t)NB_*(G3+1);
    const size_t cursor_ints = (size_t)NB_*G3;
    const size_t sort_off = ((counts_ints + cursor_ints)*4 + 15) & ~(size_t)15;
    const size_t need = sort_off + sizeof(float4)*(size_t)NB_*NP_;

    if (d_ws != nullptr && ws_size >= need) {
        int* counts  = (int*)d_ws;
        int* cursors = counts + counts_ints;
        float4* sorted = (float4*)((char*)d_ws + sort_off);
        hipMemsetAsync(counts, 0, counts_ints*sizeof(int), stream);
        knn_hist   <<<(NB_*NP_ + TPB-1)/TPB, TPB, 0, stream>>>(pts, counts);
        knn_prefix <<<NB_, PTPB, 0, stream>>>(counts, cursors);
        knn_scatter<<<(NB_*NP_ + TPB-1)/TPB, TPB, 0, stream>>>(pts, cursors, sorted);
        knn_search <<<NB_*NQ_/4, TPB, 0, stream>>>(qrs, counts, sorted, out);
    } else {
        knn_fallback<<<NB_*NQ_/QPB, TPB, 0, stream>>>(pts, qrs, out);
    }
}

// Round 31
// 87.091 us; speedup vs baseline: 1.1735x; 1.1735x over previous
//
#include <hip/hip_runtime.h>

#define NP_   16384
#define NQ_   8192
#define NB_   2
#define K_    16
#define TPB   256
#define PTPB  1024

#define GD    20
#define G3    (GD*GD*GD)          // 8000 cells per batch
#define ORG   (-4.25f)
#define W     (8.5f / 20.0f)      // 0.425
#define INVW  (20.0f / 8.5f)

#define IDX_OFF 0
#define RS_OFF  (NB_*NQ_*K_)      // 262144
#define RS_N    (NB_*NQ_+1)       // 16385
#define DST_OFF (RS_OFF + RS_N)   // 278529

typedef unsigned long long ull;
typedef float f32x2 __attribute__((ext_vector_type(2)));

__device__ __forceinline__ int mbcnt64(ull m) {
    return __builtin_amdgcn_mbcnt_hi((unsigned)(m >> 32),
           __builtin_amdgcn_mbcnt_lo((unsigned)m, 0));
}

__device__ __forceinline__ int cell_of(float x, float y, float z) {
    int ix = (int)floorf((x - ORG) * INVW); ix = min(max(ix, 0), GD-1);
    int iy = (int)floorf((y - ORG) * INVW); iy = min(max(iy, 0), GD-1);
    int iz = (int)floorf((z - ORG) * INVW); iz = min(max(iz, 0), GD-1);
    return (ix*GD + iy)*GD + iz;
}

// ---------------- fused build: zero + hist + prefix + scatter (1 block/batch) ----------------
__global__ __launch_bounds__(PTPB) void knn_build(const float* __restrict__ pts,
                                                  int* __restrict__ counts,
                                                  float4* __restrict__ sorted) {
    __shared__ int lcnt[G3];                  // 32KB
    __shared__ int wsum[PTPB/64];
    const int b = blockIdx.x, tid = threadIdx.x;
    const int lane = tid & 63, w = tid >> 6;
    int* cg = counts + b*(G3+1);

    for (int i = tid; i < G3; i += PTPB) lcnt[i] = 0;
    __syncthreads();

    // histogram via LDS atomics
    for (int i = tid; i < NP_; i += PTPB) {
        int gi = b*NP_ + i;
        atomicAdd(&lcnt[cell_of(pts[gi*3], pts[gi*3+1], pts[gi*3+2])], 1);
    }
    __syncthreads();

    // exclusive prefix: lcnt -> start offsets (also written to global)
    const int CPT = (G3 + PTPB - 1) / PTPB;   // 8 (guarded)
    int base = tid * CPT;
    int tsum = 0;
    for (int j = 0; j < CPT; ++j) { int ix = base+j; if (ix < G3) tsum += lcnt[ix]; }
    int v = tsum;
    #pragma unroll
    for (int off = 1; off < 64; off <<= 1) {
        int t = __shfl_up(v, off);
        if (lane >= off) v += t;
    }
    if (lane == 63) wsum[w] = v;
    __syncthreads();
    int wbase = 0;
    for (int k = 0; k < w; ++k) wbase += wsum[k];
    int run = wbase + v - tsum;
    __syncthreads();                          // all reads of lcnt done before overwrite
    for (int j = 0; j < CPT; ++j) {
        int ix = base+j;
        if (ix < G3) {
            int c = lcnt[ix];
            lcnt[ix] = run;                   // becomes the scatter cursor
            cg[ix] = run;                     // starts for the search kernel
            run += c;
        }
    }
    if (tid == PTPB-1) cg[G3] = run;          // sentinel = 16384
    __syncthreads();

    // scatter via LDS cursor atomics
    for (int i = tid; i < NP_; i += PTPB) {
        int gi = b*NP_ + i;
        float x = pts[gi*3], y = pts[gi*3+1], z = pts[gi*3+2];
        int pos = atomicAdd(&lcnt[cell_of(x, y, z)], 1);
        sorted[(size_t)b*NP_ + pos] = make_float4(x, y, z, __int_as_float(i));
    }
}

// ---------------- search kernel (R29 verbatim: bootstrap + depth-2 pipeline) ----------------
__global__ __launch_bounds__(TPB, 6) void knn_search(
        const float* __restrict__ qrs,
        const int* __restrict__ starts,
        const float4* __restrict__ sorted,
        float* __restrict__ out)
{
    // Validated exact-match formula (R6): sq,sp fwd noFMA; ip fwd FMA chain;
    // d = fmaf(-2, ip, sq+sp). Candidates sorted by lex (d, idx) -> stable.
    #pragma clang fp contract(off)
    __shared__ float2 buf[4][128];

    const int tid  = threadIdx.x;
    const int lane = tid & 63;
    const int wv   = tid >> 6;
    const int gq   = blockIdx.x*4 + wv;
    const int batch = gq >> 13;
    const int gofs  = batch * NP_;
    const int sb    = batch * (G3+1);
    const float4* spts = sorted + (size_t)batch * NP_;

    const float qx = qrs[gq*3+0], qy = qrs[gq*3+1], qz = qrs[gq*3+2];
    const float sq = qx*qx + qy*qy + qz*qz;   // fwd, no FMA

    int cx = (int)floorf((qx - ORG) * INVW); cx = min(max(cx,0), GD-1);
    int cy = (int)floorf((qy - ORG) * INVW); cy = min(max(cy,0), GD-1);
    int cz = (int)floorf((qz - ORG) * INVW); cz = min(max(cz,0), GD-1);

    const float INF = __int_as_float(0x7f800000);
    float md = INF; int mi = 0x7fffffff;      // master sorted-16 (lanes 0-15)
    float th = INF;
    int cnt = 0;

    auto drain = [&]() {
        int rounds = (cnt + 63) >> 6;
        for (int r = 0; r < rounds; ++r) {
            int pos = (r << 6) + lane;
            float nd = INF; int ni = 0x7fffffff;
            if (pos < cnt) { float2 e = buf[wv][pos]; nd = e.x; ni = __float_as_int(e.y); }
            // 64-lane bitonic sort ascending by (d, idx)
            #pragma unroll
            for (int m = 2; m <= 64; m <<= 1) {
                #pragma unroll
                for (int j = m >> 1; j >= 1; j >>= 1) {
                    float od = __shfl_xor(nd, j);
                    int   oi = __shfl_xor(ni, j);
                    bool pl = (od < nd) || (od == nd && oi < ni);
                    bool keepmin = ((lane & j) == 0) == ((lane & m) == 0);
                    if (keepmin == pl) { nd = od; ni = oi; }
                }
            }
            // Batcher halver: master[s] vs cand[15-s]
            float cd = __shfl(nd, 15 - (lane & 15));
            int   ci = __shfl(ni, 15 - (lane & 15));
            bool take = (cd < md) || (cd == md && ci < mi);
            if (take) { md = cd; mi = ci; }
            #pragma unroll
            for (int j = 8; j >= 1; j >>= 1) {
                float od = __shfl_xor(md, j, 16);
                int   oi = __shfl_xor(mi, j, 16);
                bool pl = (od < md) || (od == md && oi < mi);
                if ((((lane & 15) & j) == 0) == pl) { md = od; mi = oi; }
            }
        }
        cnt = 0;
        th = __shfl(md, 15);                  // current 16th-best (INF if <16)
    };

    // process one loaded candidate batch: distance, filter, append
    auto process = [&](float4 p, bool act) {
        float d = INF; int idx = 0x7fffffff;
        if (act) {
            float spw = p.x*p.x + p.y*p.y + p.z*p.z;   // fwd, no FMA
            float ip = fmaf(p.z, qz, fmaf(p.y, qy, __fmul_rn(p.x, qx)));
            d = fmaf(-2.0f, ip, sq + spw);
            idx = __float_as_int(p.w);
        }
        bool pass = act && (d <= th);          // <= : tie-safe superset
        ull mk = __ballot(pass);
        if (mk) {
            int sl = cnt + mbcnt64(mk);
            if (pass) buf[wv][sl] = make_float2(d, __int_as_float(idx));
            cnt += (int)__popcll(mk);
            if (cnt >= 64) drain();            // max before = 63, +64 <= 127
        }
    };

    // ---- bootstrap: own cell first (coalesced), establishes finite th ----
    {
        int cid0 = (cx*GD + cy)*GD + cz;
        int st0 = starts[sb + cid0];
        int n0  = starts[sb + cid0 + 1] - st0;
        for (int b0 = 0; b0 < n0; b0 += 64) {
            int o = b0 + lane;
            bool act = o < n0;
            float4 p = make_float4(0,0,0,0);
            if (act) p = spts[st0 + o];
            process(p, act);
        }
        if (cnt > 0) drain();
    }

    for (int R = 1; R <= GD; ++R) {
        const int S = 2*R + 1;
        const int F = S*S;
        const int lat = 4*(S-1);
        const int total = (R == 1) ? 27 : (2*F + (S-2)*lat);

        for (int cb = 0; cb < total; cb += 64) {
            int cidx = cb + lane;
            int n = 0, st = 0;
            if (cidx < total) {
                int di, dj, dk;
                if (R == 1) {                 // 3x3x3 box (const divisions)
                    di = cidx/9 - 1; int r9 = cidx - (cidx/9)*9;
                    dj = r9/3 - 1;   dk = r9 - (r9/3)*3 - 1;
                } else if (cidx < F) {        // -x face
                    di = -R; int t = cidx; int q = t/S; dj = q - R; dk = t - q*S - R;
                } else if (cidx < 2*F) {      // +x face
                    di =  R; int t = cidx - F; int q = t/S; dj = q - R; dk = t - q*S - R;
                } else {                      // lateral perimeter walk
                    int t = cidx - 2*F;
                    int layer = t/lat; int pos = t - layer*lat;
                    di = layer + 1 - R;       // di in (-R, R)
                    int side = pos/(S-1); int u = pos - side*(S-1);
                    if      (side == 0) { dj = -R;     dk = -R + u; }
                    else if (side == 1) { dj = -R + u; dk =  R;     }
                    else if (side == 2) { dj =  R;     dk =  R - u; }
                    else                { dj =  R - u; dk = -R;     }
                }
                bool own = (di == 0) && (dj == 0) && (dk == 0);   // already done
                int ii = cx+di, jj = cy+dj, kk = cz+dk;
                if (!own && ii>=0 && jj>=0 && kk>=0 && ii<GD && jj<GD && kk<GD) {
                    // per-cell Euclidean lower bound (th finite after bootstrap)
                    float lox = ORG + (float)ii * W;
                    float loy = ORG + (float)jj * W;
                    float loz = ORG + (float)kk * W;
                    float dx = fmaxf(0.0f, fmaxf(lox - qx, qx - (lox + W)));
                    float dy = fmaxf(0.0f, fmaxf(loy - qy, qy - (loy + W)));
                    float dz = fmaxf(0.0f, fmaxf(loz - qz, qz - (loz + W)));
                    float mind2 = dx*dx + dy*dy + dz*dz;
                    if (mind2 <= th + 1e-3f) {    // stale th only over-admits
                        int cid = (ii*GD + jj)*GD + kk;
                        st = starts[sb + cid];
                        n  = starts[sb + cid + 1] - st;
                    }
                }
            }
            // wave-wide exclusive prefix sum of n
            int pex = n;
            #pragma unroll
            for (int off = 1; off < 64; off <<= 1) {
                int t2 = __shfl_up(pex, off);
                if (lane >= off) pex += t2;
            }
            int T = __shfl(pex, 63);          // total candidates this chunk
            pex -= n;                         // exclusive prefix
            if (T == 0) continue;

            // register-only bsearch + load issue for batch starting at bb
            auto fetchB = [&](int bb, float4& p, bool& act) {
                int sI = bb + lane;
                int lo = 0;
                #pragma unroll
                for (int j = 32; j >= 1; j >>= 1) {
                    int m = lo + j;
                    int pv = __shfl(pex, m);
                    if (pv <= sI) lo = m;
                }
                int stL = __shfl(st, lo);
                int pL  = __shfl(pex, lo);
                act = sI < T;
                if (act) p = spts[stL + (sI - pL)];
            };

            // depth-2 software pipeline over batches
            float4 pA = make_float4(0,0,0,0), pB = make_float4(0,0,0,0);
            bool aA = false, aB = false;
            fetchB(0, pA, aA);
            if (64 < T) fetchB(64, pB, aB);
            for (int bb = 0; bb < T; bb += 64) {
                float4 pN = make_float4(0,0,0,0); bool aN = false;
                if (bb + 128 < T) fetchB(bb + 128, pN, aN);
                process(pA, aA);
                pA = pB; aA = aB;
                pB = pN; aB = aN;
            }
        }
        if (cnt > 0) drain();                  // tighten th for next shell's prune
        // termination (th only shrinks -> conservative)
        float bd = INF;
        if (cx - R > 0)      bd = fminf(bd, qx - (ORG + (float)(cx - R) * W));
        if (cx + R < GD - 1) bd = fminf(bd, (ORG + (float)(cx + R + 1) * W) - qx);
        if (cy - R > 0)      bd = fminf(bd, qy - (ORG + (float)(cy - R) * W));
        if (cy + R < GD - 1) bd = fminf(bd, (ORG + (float)(cy + R + 1) * W) - qy);
        if (cz - R > 0)      bd = fminf(bd, qz - (ORG + (float)(cz - R) * W));
        if (cz + R < GD - 1) bd = fminf(bd, (ORG + (float)(cz + R + 1) * W) - qz);
        if (bd * bd > th + 1e-3f) break;       // margin >> formula/geom error
    }
    drain();                                   // flush leftovers before output

    if (lane < K_) {
        out[IDX_OFF + gq*K_ + lane] = (float)(mi + gofs);
        out[DST_OFF + gq*K_ + lane] = fmaxf(md, 0.0f);
    }
    int gt = blockIdx.x*TPB + tid;
    if (gt < RS_N) out[RS_OFF + gt] = (float)(gt * K_);
}

// ---------------- fallback: R21 kernel (passed, 114 us) ----------------
#define QPB   16
#define TILE  1024
#define NTILES (NP_/TILE)
#define GPT   (TILE/64)
#define CBUF  80

__global__ __launch_bounds__(TPB, 4) void knn_fallback(const float* __restrict__ pts,
                                                       const float* __restrict__ qrs,
                                                       float* __restrict__ out)
{
    #pragma clang fp contract(off)
    __shared__ float4 tile[TILE];
    __shared__ float2 buf[QPB][CBUF];
    const int tid  = threadIdx.x;
    const int lane = tid & 63;
    const int s    = lane & 15;
    const int g    = lane >> 4;
    const int bq   = tid >> 4;
    const int gq   = blockIdx.x * QPB + bq;
    const int batch = gq >> 13;
    const int gofs  = batch * NP_;
    const float* pb = pts + (size_t)gofs * 3;
    const int qb   = (tid >> 6) << 2;
    float qxv[4], qyv[4], qzv[4], sqv[4];
    #pragma unroll
    for (int qi = 0; qi < 4; ++qi) {
        const float* qp = qrs + (size_t)(blockIdx.x * QPB + qb + qi) * 3;
        qxv[qi] = qp[0]; qyv[qi] = qp[1]; qzv[qi] = qp[2];
        sqv[qi] = qxv[qi]*qxv[qi] + qyv[qi]*qyv[qi] + qzv[qi]*qzv[qi];
    }
    const f32x2 qx01 = {qxv[0], qxv[1]}, qx23 = {qxv[2], qxv[3]};
    const f32x2 qy01 = {qyv[0], qyv[1]}, qy23 = {qyv[2], qyv[3]};
    const f32x2 qz01 = {qzv[0], qzv[1]}, qz23 = {qzv[2], qzv[3]};
    const f32x2 sq01 = {sqv[0], sqv[1]}, sq23 = {sqv[2], sqv[3]};
    const f32x2 n2   = {-2.0f, -2.0f};
    const float INF = __int_as_float(0x7f800000);
    float hd = INF; int hi = 0x7fffffff;
    float th0 = INF, th1 = INF, th2 = INF, th3 = INF;
    int cnt0 = 0, cnt1 = 0, cnt2 = 0, cnt3 = 0;
    auto drain = [&]() {
        int cmax = max(max(cnt0, cnt1), max(cnt2, cnt3));
        int mycnt = (g==0) ? cnt0 : (g==1) ? cnt1 : (g==2) ? cnt2 : cnt3;
        for (int r = 0; r < cmax; r += K_) {
            float nd = INF; int ni = 0x7fffffff;
            int pos = r + s;
            if (pos < mycnt) { float2 e = buf[bq][pos]; nd = e.x; ni = __float_as_int(e.y); }
            #pragma unroll
            for (int m = 2; m <= 16; m <<= 1) {
                #pragma unroll
                for (int j = m >> 1; j > 0; j >>= 1) {
                    float od = __shfl_xor(nd, j);
                    int   oi = __shfl_xor(ni, j);
                    bool pl = (od < nd) || (od == nd && oi < ni);
                    bool keepmin = ((s & j) == 0) == ((s & m) == 0);
                    if (keepmin == pl) { nd = od; ni = oi; }
                }
            }
            float od = __shfl_xor(nd, 15);
            int   oi = __shfl_xor(ni, 15);
            bool pl = (od < hd) || (od == hd && oi < hi);
            if (pl) { hd = od; hi = oi; }
            #pragma unroll
            for (int j = 8; j > 0; j >>= 1) {
                float od2 = __shfl_xor(hd, j);
                int   oi2 = __shfl_xor(hi, j);
                bool pl2 = (od2 < hd) || (od2 == hd && oi2 < hi);
                if (((s & j) == 0) == pl2) { hd = od2; hi = oi2; }
            }
        }
        cnt0 = cnt1 = cnt2 = cnt3 = 0;
        th0 = __shfl(hd, 15, 64); th1 = __shfl(hd, 31, 64);
        th2 = __shfl(hd, 47, 64); th3 = __shfl(hd, 63, 64);
    };
    for (int t = 0; t < NTILES; ++t) {
        __syncthreads();
        #pragma unroll
        for (int k = 0; k < TILE/TPB; ++k) {
            int lp = tid + k*TPB; int gp = t*TILE + lp;
            float x = pb[gp*3+0], y = pb[gp*3+1], z = pb[gp*3+2];
            float sp = x*x + y*y + z*z;
            tile[lp] = make_float4(x, y, z, sp);
        }
        __syncthreads();
        #pragma unroll 4
        for (int gi = 0; gi < GPT; ++gi) {
            float4 p = tile[gi*64 + lane];
            f32x2 x2 = {p.x, p.x}, y2 = {p.y, p.y}, z2 = {p.z, p.z};
            f32x2 sps = {p.w, p.w};
            f32x2 ip01 = __builtin_elementwise_fma(z2, qz01,
                         __builtin_elementwise_fma(y2, qy01, x2*qx01));
            f32x2 ip23 = __builtin_elementwise_fma(z2, qz23,
                         __builtin_elementwise_fma(y2, qy23, x2*qx23));
            f32x2 d01 = __builtin_elementwise_fma(n2, ip01, sq01 + sps);
            f32x2 d23 = __builtin_elementwise_fma(n2, ip23, sq23 + sps);
            float d0 = d01.x, d1 = d01.y, d2 = d23.x, d3 = d23.y;
            ull m0 = __ballot(d0 <= th0);
            ull m1 = __ballot(d1 <= th1);
            ull m2 = __ballot(d2 <= th2);
            ull m3 = __ballot(d3 <= th3);
            if (m0 | m1 | m2 | m3) {
                const float fpid = __int_as_float(t*TILE + gi*64 + lane);
                if (m0) { int sl = cnt0 + mbcnt64(m0);
                    if (d0 <= th0) buf[qb+0][sl] = make_float2(d0, fpid);
                    cnt0 += (int)__popcll(m0); }
                if (m1) { int sl = cnt1 + mbcnt64(m1);
                    if (d1 <= th1) buf[qb+1][sl] = make_float2(d1, fpid);
                    cnt1 += (int)__popcll(m1); }
                if (m2) { int sl = cnt2 + mbcnt64(m2);
                    if (d2 <= th2) buf[qb+2][sl] = make_float2(d2, fpid);
                    cnt2 += (int)__popcll(m2); }
                if (m3) { int sl = cnt3 + mbcnt64(m3);
                    if (d3 <= th3) buf[qb+3][sl] = make_float2(d3, fpid);
                    cnt3 += (int)__popcll(m3); }
                if ((cnt0 | cnt1 | cnt2 | cnt3) >= K_) drain();
            }
        }
    }
    drain();
    out[IDX_OFF + gq*K_ + s] = (float)(hi + gofs);
    out[DST_OFF + gq*K_ + s] = fmaxf(hd, 0.0f);
    int gt = blockIdx.x * TPB + tid;
    if (gt < RS_N) out[RS_OFF + gt] = (float)(gt * K_);
}

extern "C" void kernel_launch(void* const* d_in, const int* in_sizes, int n_in,
                              void* d_out, int out_size, void* d_ws, size_t ws_size,
                              hipStream_t stream)
{
    const float* pts = (const float*)d_in[0];
    const float* qrs = (const float*)d_in[1];
    float* out = (float*)d_out;
    (void)in_sizes; (void)n_in; (void)out_size;

    const size_t counts_ints = (size_t)NB_*(G3+1);
    const size_t sort_off = (counts_ints*4 + 15) & ~(size_t)15;
    const size_t need = sort_off + sizeof(float4)*(size_t)NB_*NP_;

    if (d_ws != nullptr && ws_size >= need) {
        int* counts  = (int*)d_ws;
        float4* sorted = (float4*)((char*)d_ws + sort_off);
        knn_build <<<NB_, PTPB, 0, stream>>>(pts, counts, sorted);
        knn_search<<<NB_*NQ_/4, TPB, 0, stream>>>(qrs, counts, sorted, out);
    } else {
        knn_fallback<<<NB_*NQ_/QPB, TPB, 0, stream>>>(pts, qrs, out);
    }
}